// Round 15
// baseline (150.619 us; speedup 1.0000x reference)
//
#include <hip/hip_runtime.h>

// ---------------------------------------------------------------------------
// Attention block, faithful to reference quirks:
//  - raw reshape head split: per (b,h) Q/K/V are contiguous [2048,64] slabs
//  - softmax over QUERY axis: attn[q,k] = exp(s[q,k]) / sum_q exp(s[q,k])
// Algebra: Z[k] = sum_q exp(s); fold 1/Z into V (Vn = V/Z); out = exp(S)@Vn.
// Q carries 0.125*log2(e) so exp is a single v_exp_f32 (2^x).
// k_colv emits BOTH PV operands fragment-linear:
//   VF: 16B chunk per (tp,dt,wid,lane) — Vn B-fragments
//   KF: 16B chunk per (tp,kc,ks,lane)  — K A-fragments (from its own kf regs;
//       V loaded LATE to pay the register bill — r11's 144-VGPR lesson)
// k_attn: all loads coalesced dwordx4, NO LDS/barriers in main loop, plus
// explicit 1-ahead K-fragment prefetch (named dbuf, full unroll) to hide
// the front-of-iteration L2 latency.
// TOOLCHAIN LESSON (r10, r13): __launch_bounds__ 2nd arg caps VGPR far below
// the documented waves/EU formula (asked 5 -> 48, asked 4 -> 64) => banned.
// KF aliases Xb (dead after k_gemm_qkv; stream-ordered => safe every replay).
// ---------------------------------------------------------------------------

typedef unsigned short ush;
typedef short s16v8 __attribute__((ext_vector_type(8)));
typedef float f32x4 __attribute__((ext_vector_type(4)));

#define BATCH_STRIDE 1048576   // T*D = 2048*512
#define HEAD_STRIDE  131072    // T*hd = 2048*64
#define ALPHA_Q 0.18033688011112042f   // 0.125 * log2(e)

__device__ __forceinline__ ush f2bf(float f) {
  unsigned int u = __builtin_bit_cast(unsigned int, f);
  u = (u + 0x7FFFu + ((u >> 16) & 1u)) >> 16;   // round-to-nearest-even
  return (ush)u;
}
__device__ __forceinline__ float bf2f(ush u) {
  return __builtin_bit_cast(float, (unsigned int)u << 16);
}
// fast pack two f32 -> 2xbf16 u32 (round-half-up; P is positive & well-scaled)
__device__ __forceinline__ unsigned int bfpack(float lo, float hi) {
  unsigned int ul = __builtin_bit_cast(unsigned int, lo) + 0x8000u;
  unsigned int uh = __builtin_bit_cast(unsigned int, hi) + 0x8000u;
  return (uh & 0xFFFF0000u) | (ul >> 16);
}
__device__ __forceinline__ float fexp2(float x) {
#if __has_builtin(__builtin_amdgcn_exp2f)
  return __builtin_amdgcn_exp2f(x);
#else
  return exp2f(x);
#endif
}

// swizzled LDS tile (8-chunk rows): 16B chunk at slot = row*8 + (ch ^ (row&7))
__device__ __forceinline__ s16v8 ldsfrag(const ush* base, int row, int ch) {
  return *(const s16v8*)(base + (((row) << 3) + ((ch) ^ ((row) & 7))) * 8);
}

__device__ __forceinline__ f32x4 mfma16(s16v8 a, s16v8 b, f32x4 c) {
  return __builtin_amdgcn_mfma_f32_16x16x32_bf16(a, b, c, 0, 0, 0);
}

__device__ __forceinline__ void gll16(const ush* g, ush* l) {
  __builtin_amdgcn_global_load_lds(
      (const __attribute__((address_space(1))) void*)g,
      (__attribute__((address_space(3))) void*)l, 16, 0, 0);
}

// ---------------------------------------------------------------------------
// f32 -> bf16 for X and the 4 weight matrices
// ---------------------------------------------------------------------------
__global__ __launch_bounds__(256) void k_convert(
    const float* __restrict__ X, const float* __restrict__ Wq,
    const float* __restrict__ Wk, const float* __restrict__ Wv,
    const float* __restrict__ Wo, ush* __restrict__ Xb, ush* __restrict__ Wb) {
  int id = blockIdx.x * 256 + threadIdx.x;
  const float* src;
  ush* dst;
  int idx;
  if (id < 1048576) {
    src = X; dst = Xb; idx = id;
  } else {
    int t = id - 1048576;
    int w = t >> 16;
    idx = t & 65535;
    src = (w == 0) ? Wq : (w == 1) ? Wk : (w == 2) ? Wv : Wo;
    dst = Wb + w * 262144;
  }
  float4 v = ((const float4*)src)[idx];
  ushort4 o;
  o.x = f2bf(v.x); o.y = f2bf(v.y); o.z = f2bf(v.z); o.w = f2bf(v.w);
  ((ushort4*)dst)[idx] = o;
}

// ---------------------------------------------------------------------------
// 2-phase dbuf GEMM, BM=128 BN=128 BK=64 (verified round 2)
// ---------------------------------------------------------------------------
__device__ __forceinline__ void stage_tile(
    const ush* __restrict__ A, const ush* __restrict__ W,
    ush* lds, int m0, int n0, int k0, int wid, int lane) {
#pragma unroll
  for (int i = 0; i < 4; i++) {
    int s = wid * 4 + i;
    int row = s * 8 + (lane >> 3);
    int ch = (lane & 7) ^ (lane >> 3);
    gll16(A + (size_t)(m0 + row) * 512 + k0 + ch * 8, lds + s * 512);
    gll16(W + (size_t)(n0 + row) * 512 + k0 + ch * 8, lds + 8192 + s * 512);
  }
}

template <int OUTMODE>
__device__ __forceinline__ void gemm2(
    const ush* __restrict__ A, const ush* __restrict__ W,
    ush* __restrict__ Obf, float* __restrict__ Ofp,
    const float* __restrict__ bias, int m0, int n0) {
  __shared__ __align__(16) ush SM[2][16384];
  const int tid = threadIdx.x, lane = tid & 63, wid = tid >> 6;
  const int l16 = lane & 15, lg = lane >> 4;
  const int wr = wid >> 1, wc = wid & 1;

  const f32x4 z4 = {0.f, 0.f, 0.f, 0.f};
  f32x4 acc[4][4];
#pragma unroll
  for (int i = 0; i < 4; i++)
#pragma unroll
    for (int j = 0; j < 4; j++) acc[i][j] = z4;

  stage_tile(A, W, &SM[0][0], m0, n0, 0, wid, lane);
  __syncthreads();
  int cur = 0;
#pragma unroll 1
  for (int t = 0; t < 8; t++) {
    if (t < 7) stage_tile(A, W, &SM[cur ^ 1][0], m0, n0, (t + 1) * 64, wid, lane);
    const ush* At = &SM[cur][0];
    const ush* Bt = &SM[cur][8192];
    s16v8 af[4][2], bf2[4][2];
#pragma unroll
    for (int ms = 0; ms < 4; ms++)
#pragma unroll
      for (int ks = 0; ks < 2; ks++)
        af[ms][ks] = ldsfrag(At, wr * 64 + ms * 16 + l16, ks * 4 + lg);
#pragma unroll
    for (int ns = 0; ns < 4; ns++)
#pragma unroll
      for (int ks = 0; ks < 2; ks++)
        bf2[ns][ks] = ldsfrag(Bt, wc * 64 + ns * 16 + l16, ks * 4 + lg);
#pragma unroll
    for (int ms = 0; ms < 4; ms++)
#pragma unroll
      for (int ns = 0; ns < 4; ns++)
#pragma unroll
        for (int ks = 0; ks < 2; ks++)
          acc[ms][ns] = mfma16(af[ms][ks], bf2[ns][ks], acc[ms][ns]);
    __syncthreads();
    cur ^= 1;
  }

  if (OUTMODE == 0) {
    const int gc0 = n0 + wc * 64;
    const float alpha = (gc0 < 512) ? ALPHA_Q : 1.0f;  // Q carries 1/8*log2e
    ush* cw = &SM[0][0] + wid * 4096;
#pragma unroll
    for (int ms = 0; ms < 4; ms++)
#pragma unroll
      for (int ns = 0; ns < 4; ns++)
#pragma unroll
        for (int r = 0; r < 4; r++) {
          int row = ms * 16 + lg * 4 + r;
          int col = ns * 16 + l16;
          int sw = (((col >> 3) ^ (row & 7)) << 3) + (col & 7);
          cw[row * 64 + sw] = f2bf(acc[ms][ns][r] * alpha);
        }
    __syncthreads();
    const int z = gc0 >> 9, jl = gc0 & 511;
    ush* og = Obf + (size_t)z * 4194304 + (size_t)(m0 + wr * 64) * 512 + jl;
#pragma unroll
    for (int i = 0; i < 8; i++) {
      int row = i * 8 + (lane >> 3), ch = lane & 7;
      s16v8 v = ldsfrag(cw, row, ch);
      *(s16v8*)(og + (size_t)row * 512 + ch * 8) = v;
    }
  } else {
#pragma unroll
    for (int ms = 0; ms < 4; ms++)
#pragma unroll
      for (int ns = 0; ns < 4; ns++) {
        int gcol = n0 + wc * 64 + ns * 16 + l16;
#pragma unroll
        for (int r = 0; r < 4; r++) {
          int grow = m0 + wr * 64 + ms * 16 + lg * 4 + r;
          Ofp[(size_t)grow * 512 + gcol] = acc[ms][ns][r] + bias[gcol];
        }
      }
  }
}

__global__ __launch_bounds__(256) void k_gemm_qkv(
    const ush* __restrict__ Xb, const ush* __restrict__ Wb,
    ush* __restrict__ QKV) {
  gemm2<0>(Xb, Wb, QKV, nullptr, nullptr, blockIdx.x * 128, blockIdx.y * 128);
}

__global__ __launch_bounds__(256) void k_gemm_out(
    const ush* __restrict__ AO, const ush* __restrict__ Wob,
    float* __restrict__ out, const float* __restrict__ bias) {
  gemm2<1>(AO, Wob, nullptr, out, bias, blockIdx.x * 128, blockIdx.y * 128);
}

// ---------------------------------------------------------------------------
// k_colv: per (tp: 128 k-rows, bh):
//   1) K fragments -> regs; store this wave's slices to KF (kc = 2*wid, 2*wid+1)
//   2) Z[k] = sum_q 2^(s'[q,k]) via swapped-QK (K frags in regs, Q direct)
//   3) V loaded LATE (post-Z) into LDS; Vn = V/Z emitted fragment-linear
// grid: 512 = 8 xcd x 4 bh x 16 tp.
// ---------------------------------------------------------------------------
__global__ __launch_bounds__(256) void k_colv(
    const ush* __restrict__ Qb, const ush* __restrict__ Kb,
    const ush* __restrict__ Vb, ush* __restrict__ VF, ush* __restrict__ KF) {
  const int wg = blockIdx.x;
  const int xcd = wg & 7, slot = wg >> 3;
  const int bh = xcd * 4 + (slot >> 4), tp = slot & 15;
  const int b = bh >> 3, h = bh & 7;
  const size_t base = (size_t)b * BATCH_STRIDE + h * HEAD_STRIDE;
  const ush* Qg = Qb + base;
  const ush* Kg = Kb + base + tp * 8192;   // 128 k-rows x 64
  const ush* Vg = Vb + base + tp * 8192;
  ush* vfh = VF + base + tp * 8192;        // 1024 chunks x 8 shorts
  ush* kfh = KF + base;                    // fragment-linear K (whole head)

  __shared__ float Zp[512];
  __shared__ float invZ[128];
  __shared__ __align__(16) ush L[128][72];

  const int tid = threadIdx.x, lane = tid & 63, wid = tid >> 6;
  const int l16 = lane & 15, lg = lane >> 4;

  // K fragments (A-operand): rows kc*16+l16, hd = ks*32 + lg*8..+7
  s16v8 kf[8][2];
#pragma unroll
  for (int kc = 0; kc < 8; kc++)
#pragma unroll
    for (int ks = 0; ks < 2; ks++)
      kf[kc][ks] = *(const s16v8*)(Kg + (size_t)(kc * 16 + l16) * 64 + ks * 32 + lg * 8);

  // store this wave's K fragment slices to KF (kc = 2*wid, 2*wid+1)
#pragma unroll
  for (int kc2 = 0; kc2 < 2; kc2++) {
    int kc = wid * 2 + kc2;
#pragma unroll
    for (int ks = 0; ks < 2; ks++)
      *(s16v8*)(kfh + ((size_t)((tp * 8 + kc) * 2 + ks) * 64 + lane) * 8) =
          kf[kc][ks];
  }

  const f32x4 z4 = {0.f, 0.f, 0.f, 0.f};
  f32x4 zacc[8];
#pragma unroll
  for (int kc = 0; kc < 8; kc++) zacc[kc] = z4;

#pragma unroll 1
  for (int t = 0; t < 8; t++) {
    size_t q0 = (size_t)(t * 4 + wid) * 64;
#pragma unroll
    for (int ms = 0; ms < 4; ms++) {
      const ush* qrow = Qg + (q0 + ms * 16 + l16) * 64;
      s16v8 qf0 = *(const s16v8*)(qrow + lg * 8);
      s16v8 qf1 = *(const s16v8*)(qrow + 32 + lg * 8);
      __builtin_amdgcn_s_setprio(1);
#pragma unroll
      for (int kc = 0; kc < 8; kc++) {
        f32x4 s = mfma16(kf[kc][0], qf0, z4);
        s = mfma16(kf[kc][1], qf1, s);
#pragma unroll
        for (int r = 0; r < 4; r++) zacc[kc][r] += fexp2(s[r]);
      }
      __builtin_amdgcn_s_setprio(0);
    }
  }

  // V tile (128x64) loaded LATE into LDS [k][d] (padded rows)
#pragma unroll
  for (int i = 0; i < 4; i++) {
    int cid = tid * 4 + i;
    uint4 v = *(const uint4*)(Vg + (size_t)(cid >> 3) * 64 + (cid & 7) * 8);
    *(uint4*)(&L[cid >> 3][(cid & 7) * 8]) = v;
  }

  // per-wave partial: sum over the wave's 512 q (l16 groups)
#pragma unroll
  for (int kc = 0; kc < 8; kc++)
#pragma unroll
    for (int r = 0; r < 4; r++) {
      float v = zacc[kc][r];
      v += __shfl_xor(v, 1); v += __shfl_xor(v, 2);
      v += __shfl_xor(v, 4); v += __shfl_xor(v, 8);
      if (l16 == 0) Zp[wid * 128 + kc * 16 + lg * 4 + r] = v;
    }
  __syncthreads();
  if (tid < 128)
    invZ[tid] = 1.0f / (Zp[tid] + Zp[128 + tid] + Zp[256 + tid] + Zp[384 + tid]);
  __syncthreads();

  // emit fragment-linear VF: chunk c -> (dt, wid_t, lane_t)
#pragma unroll
  for (int i = 0; i < 4; i++) {
    int c = tid * 4 + i;
    int dt = c >> 8, wid_t = (c >> 6) & 3, lane_t = c & 63;
    int d = dt * 16 + (lane_t & 15);
    int kA = wid_t * 16 + ((lane_t >> 4) << 2);
    ush tmp[8];
#pragma unroll
    for (int j = 0; j < 4; j++)
      tmp[j] = f2bf(bf2f(L[kA + j][d]) * invZ[kA + j]);
#pragma unroll
    for (int j = 0; j < 4; j++)
      tmp[4 + j] = f2bf(bf2f(L[kA + 64 + j][d]) * invZ[kA + 64 + j]);
    *(uint4*)(vfh + c * 8) = *(const uint4*)tmp;
  }
}

// ---------------------------------------------------------------------------
// k_attn: out[q,d] = sum_k 2^(s'[q,k]) * Vn[k,d]
// Block: 64 q rows; 4 waves each own a 16-k slice of each 64-k tile; two
// tiles paired per iter (128 k). Swapped QK (A=K) => P in exact A-frag layout.
// K via KF, Vn via VF — all loads coalesced dwordx4; NO LDS/barriers in loop.
// Explicit 1-ahead K prefetch (named dbuf kc/kn, fully unrolled).
// ---------------------------------------------------------------------------
__global__ __launch_bounds__(256) void k_attn(
    const ush* __restrict__ Qb, const ush* __restrict__ KF,
    const ush* __restrict__ VF, ush* __restrict__ AO) {
  const int wg = blockIdx.x;
  const int xcd = wg & 7, slot = wg >> 3;
  const int bh = xcd * 4 + (slot >> 5), qb = slot & 31;
  const int b = bh >> 3, h = bh & 7;
  const size_t base = (size_t)b * BATCH_STRIDE + h * HEAD_STRIDE;
  const ush* Qg = Qb + base + qb * 4096;   // 64 q rows x 64 dims
  const ush* kfh = KF + base;              // fragment-linear K
  const ush* vfh = VF + base;              // fragment-linear Vn
  ush* aog = AO + base + qb * 4096;

  __shared__ __align__(16) char smraw[32768];  // epilogue only: 2 x 16KB

  const int tid = threadIdx.x, lane = tid & 63, wid = tid >> 6;
  const int l16 = lane & 15, lg = lane >> 4;

  // Q fragments direct from global (held whole kernel)
  s16v8 qa[4][2];
#pragma unroll
  for (int ms = 0; ms < 4; ms++)
#pragma unroll
    for (int ks = 0; ks < 2; ks++)
      qa[ms][ks] = *(const s16v8*)(Qg + (size_t)(ms * 16 + l16) * 64 + ks * 32 + lg * 8);

  const f32x4 z4 = {0.f, 0.f, 0.f, 0.f};
  f32x4 oacc[4][4];
#pragma unroll
  for (int i = 0; i < 4; i++)
#pragma unroll
    for (int j = 0; j < 4; j++) oacc[i][j] = z4;

  const ush* krow = kfh + (size_t)wid * 1024 + (size_t)lane * 8;
  const ush* vrow = vfh + (size_t)(wid * 64 + lane) * 8;

  s16v8 kc0[2], kc1[2], kn0[2], kn1[2];
  {
    const ush* kr = krow;
    kc0[0] = *(const s16v8*)(kr);
    kc0[1] = *(const s16v8*)(kr + 512);
    kc1[0] = *(const s16v8*)(kr + 4096);
    kc1[1] = *(const s16v8*)(kr + 4096 + 512);
  }

#define ATTN_BODY(T, K0, K1)                                                 \
  {                                                                          \
    uint4 vbu[4];                                                            \
    _Pragma("unroll")                                                        \
    for (int dt = 0; dt < 4; dt++)                                           \
      vbu[dt] = *(const uint4*)(vrow + (size_t)((T) * 16 + dt * 4) * 512);   \
    __builtin_amdgcn_s_setprio(1);                                           \
    _Pragma("unroll")                                                        \
    for (int ms = 0; ms < 4; ms++) {                                         \
      f32x4 sA = mfma16(K0[0], qa[ms][0], z4);                               \
      sA = mfma16(K0[1], qa[ms][1], sA);                                     \
      f32x4 sB = mfma16(K1[0], qa[ms][0], z4);                               \
      sB = mfma16(K1[1], qa[ms][1], sB);                                     \
      uint4 pu;                                                              \
      pu.x = bfpack(fexp2(sA[0]), fexp2(sA[1]));                             \
      pu.y = bfpack(fexp2(sA[2]), fexp2(sA[3]));                             \
      pu.z = bfpack(fexp2(sB[0]), fexp2(sB[1]));                             \
      pu.w = bfpack(fexp2(sB[2]), fexp2(sB[3]));                             \
      s16v8 pa = __builtin_bit_cast(s16v8, pu);                              \
      _Pragma("unroll")                                                      \
      for (int dt = 0; dt < 4; dt++)                                         \
        oacc[ms][dt] =                                                       \
            mfma16(pa, __builtin_bit_cast(s16v8, vbu[dt]), oacc[ms][dt]);    \
    }                                                                        \
    __builtin_amdgcn_s_setprio(0);                                           \
  }

#pragma unroll
  for (int tph = 0; tph < 8; tph++) {
    const int t0 = tph * 2, t1 = t0 + 1;
    {
      const ush* kr = krow + (size_t)t1 * 8192;
      kn0[0] = *(const s16v8*)(kr);
      kn0[1] = *(const s16v8*)(kr + 512);
      kn1[0] = *(const s16v8*)(kr + 4096);
      kn1[1] = *(const s16v8*)(kr + 4096 + 512);
    }
    ATTN_BODY(t0, kc0, kc1);
    if (tph < 7) {
      const ush* kr = krow + (size_t)(t0 + 2) * 8192;
      kc0[0] = *(const s16v8*)(kr);
      kc0[1] = *(const s16v8*)(kr + 512);
      kc1[0] = *(const s16v8*)(kr + 4096);
      kc1[1] = *(const s16v8*)(kr + 4096 + 512);
    }
    ATTN_BODY(t1, kn0, kn1);
  }
#undef ATTN_BODY

  // ---- cross-wave k-slice reduction: slot-major, conflict-free ----
  float* red = (float*)smraw;
  if (wid >= 2) {
    float* rg = red + (wid - 2) * 4096;
#pragma unroll
    for (int ms = 0; ms < 4; ms++)
#pragma unroll
      for (int dt = 0; dt < 4; dt++)
        *(f32x4*)(rg + (ms * 4 + dt) * 256 + lane * 4) = oacc[ms][dt];
  }
  __syncthreads();
  if (wid < 2) {
    float* rg = red + wid * 4096;
#pragma unroll
    for (int ms = 0; ms < 4; ms++)
#pragma unroll
      for (int dt = 0; dt < 4; dt++)
        oacc[ms][dt] += *(const f32x4*)(rg + (ms * 4 + dt) * 256 + lane * 4);
  }
  __syncthreads();
  if (wid == 1) {
#pragma unroll
    for (int ms = 0; ms < 4; ms++)
#pragma unroll
      for (int dt = 0; dt < 4; dt++)
        *(f32x4*)(red + (ms * 4 + dt) * 256 + lane * 4) = oacc[ms][dt];
  }
  __syncthreads();
  if (wid == 0) {
#pragma unroll
    for (int ms = 0; ms < 4; ms++)
#pragma unroll
      for (int dt = 0; dt < 4; dt++)
        oacc[ms][dt] += *(const f32x4*)(red + (ms * 4 + dt) * 256 + lane * 4);
  }
  __syncthreads();   // all reads done before out-tile overwrites region 0
  ush* ot = (ush*)smraw;   // 64x64 bf16 out tile
  if (wid == 0) {
#pragma unroll
    for (int ms = 0; ms < 4; ms++)
#pragma unroll
      for (int dt = 0; dt < 4; dt++)
#pragma unroll
        for (int r = 0; r < 4; r++)
          ot[(ms * 16 + lg * 4 + r) * 64 + dt * 16 + l16] = f2bf(oacc[ms][dt][r]);
  }
  __syncthreads();
#pragma unroll
  for (int rd = 0; rd < 2; rd++) {
    int id = rd * 256 + tid;
    *(s16v8*)(aog + id * 8) = *(const s16v8*)(ot + id * 8);
  }
}

// ---------------------------------------------------------------------------
extern "C" void kernel_launch(void* const* d_in, const int* in_sizes, int n_in,
                              void* d_out, int out_size, void* d_ws, size_t ws_size,
                              hipStream_t stream) {
  const float* X  = (const float*)d_in[0];
  const float* Wq = (const float*)d_in[1];
  const float* Wk = (const float*)d_in[2];
  const float* Wv = (const float*)d_in[3];
  const float* Wo = (const float*)d_in[4];
  const float* bo = (const float*)d_in[5];

  ush* Qb  = (ush*)d_ws;          // QKV contiguous: 3 x 4M bf16
  ush* Kb  = Qb + 4194304;
  ush* Vb  = Kb + 4194304;
  ush* VF  = Vb + 4194304;        // fragment-linear Vn per head
  ush* AO  = VF + 4194304;
  ush* Xb  = AO + 4194304;        // X bf16; KF aliases it (dead after qkv GEMM)
  ush* Wb  = Xb + 4194304;        // 4 x 262144 (Wq,Wk,Wv,Wo)
  ush* KF  = Xb;                  // fragment-linear K per head

  k_convert<<<5120, 256, 0, stream>>>(X, Wq, Wk, Wv, Wo, Xb, Wb);
  k_gemm_qkv<<<dim3(64, 12), 256, 0, stream>>>(Xb, Wb, Qb);
  k_colv<<<512, 256, 0, stream>>>(Qb, Kb, Vb, VF, KF);
  k_attn<<<1024, 256, 0, stream>>>(Qb, KF, VF, AO);
  k_gemm_out<<<dim3(64, 4), 256, 0, stream>>>(AO, Wb + 3 * 262144, (float*)d_out, bo);
}

// Round 16
// 126.849 us; speedup vs baseline: 1.1874x; 1.1874x over previous
//
#include <hip/hip_runtime.h>

// ---------------------------------------------------------------------------
// Attention block, faithful to reference quirks:
//  - raw reshape head split: per (b,h) Q/K/V are contiguous [2048,64] slabs
//  - softmax over QUERY axis: attn[q,k] = exp(s[q,k]) / sum_q exp(s[q,k])
// Algebra: Z[k] = sum_q exp(s); fold 1/Z into V (Vn = V/Z); out = exp(S)@Vn.
// Q carries 0.125*log2(e) so exp is a single v_exp_f32 (2^x).
// Fragment-linear operand buffers for k_attn (every load coalesced dwordx4):
//   VF: produced by k_colv (Vn = V/Z B-fragments)
//   KF: produced by dedicated k_kf transform (K A-fragments)
// KF production MUST be a separate kernel: r11/r15 both measured 144 VGPR
// (3 waves/SIMD) when folded into colv, regardless of V-load timing.
// k_attn: 1-ahead K-fragment prefetch (named dbuf, full unroll — r15).
// TOOLCHAIN LESSON (r10, r13): __launch_bounds__ 2nd arg caps VGPR far below
// the documented waves/EU formula (asked 5 -> 48, asked 4 -> 64) => banned.
// KF aliases Xb (dead after k_gemm_qkv; stream-ordered => safe every replay).
// ---------------------------------------------------------------------------

typedef unsigned short ush;
typedef short s16v8 __attribute__((ext_vector_type(8)));
typedef float f32x4 __attribute__((ext_vector_type(4)));

#define BATCH_STRIDE 1048576   // T*D = 2048*512
#define HEAD_STRIDE  131072    // T*hd = 2048*64
#define ALPHA_Q 0.18033688011112042f   // 0.125 * log2(e)

__device__ __forceinline__ ush f2bf(float f) {
  unsigned int u = __builtin_bit_cast(unsigned int, f);
  u = (u + 0x7FFFu + ((u >> 16) & 1u)) >> 16;   // round-to-nearest-even
  return (ush)u;
}
__device__ __forceinline__ float bf2f(ush u) {
  return __builtin_bit_cast(float, (unsigned int)u << 16);
}
// fast pack two f32 -> 2xbf16 u32 (round-half-up; P is positive & well-scaled)
__device__ __forceinline__ unsigned int bfpack(float lo, float hi) {
  unsigned int ul = __builtin_bit_cast(unsigned int, lo) + 0x8000u;
  unsigned int uh = __builtin_bit_cast(unsigned int, hi) + 0x8000u;
  return (uh & 0xFFFF0000u) | (ul >> 16);
}
__device__ __forceinline__ float fexp2(float x) {
#if __has_builtin(__builtin_amdgcn_exp2f)
  return __builtin_amdgcn_exp2f(x);
#else
  return exp2f(x);
#endif
}

// swizzled LDS tile (8-chunk rows): 16B chunk at slot = row*8 + (ch ^ (row&7))
__device__ __forceinline__ s16v8 ldsfrag(const ush* base, int row, int ch) {
  return *(const s16v8*)(base + (((row) << 3) + ((ch) ^ ((row) & 7))) * 8);
}

__device__ __forceinline__ f32x4 mfma16(s16v8 a, s16v8 b, f32x4 c) {
  return __builtin_amdgcn_mfma_f32_16x16x32_bf16(a, b, c, 0, 0, 0);
}

__device__ __forceinline__ void gll16(const ush* g, ush* l) {
  __builtin_amdgcn_global_load_lds(
      (const __attribute__((address_space(1))) void*)g,
      (__attribute__((address_space(3))) void*)l, 16, 0, 0);
}

// ---------------------------------------------------------------------------
// f32 -> bf16 for X and the 4 weight matrices
// ---------------------------------------------------------------------------
__global__ __launch_bounds__(256) void k_convert(
    const float* __restrict__ X, const float* __restrict__ Wq,
    const float* __restrict__ Wk, const float* __restrict__ Wv,
    const float* __restrict__ Wo, ush* __restrict__ Xb, ush* __restrict__ Wb) {
  int id = blockIdx.x * 256 + threadIdx.x;
  const float* src;
  ush* dst;
  int idx;
  if (id < 1048576) {
    src = X; dst = Xb; idx = id;
  } else {
    int t = id - 1048576;
    int w = t >> 16;
    idx = t & 65535;
    src = (w == 0) ? Wq : (w == 1) ? Wk : (w == 2) ? Wv : Wo;
    dst = Wb + w * 262144;
  }
  float4 v = ((const float4*)src)[idx];
  ushort4 o;
  o.x = f2bf(v.x); o.y = f2bf(v.y); o.z = f2bf(v.z); o.w = f2bf(v.w);
  ((ushort4*)dst)[idx] = o;
}

// ---------------------------------------------------------------------------
// 2-phase dbuf GEMM, BM=128 BN=128 BK=64 (verified round 2)
// ---------------------------------------------------------------------------
__device__ __forceinline__ void stage_tile(
    const ush* __restrict__ A, const ush* __restrict__ W,
    ush* lds, int m0, int n0, int k0, int wid, int lane) {
#pragma unroll
  for (int i = 0; i < 4; i++) {
    int s = wid * 4 + i;
    int row = s * 8 + (lane >> 3);
    int ch = (lane & 7) ^ (lane >> 3);
    gll16(A + (size_t)(m0 + row) * 512 + k0 + ch * 8, lds + s * 512);
    gll16(W + (size_t)(n0 + row) * 512 + k0 + ch * 8, lds + 8192 + s * 512);
  }
}

template <int OUTMODE>
__device__ __forceinline__ void gemm2(
    const ush* __restrict__ A, const ush* __restrict__ W,
    ush* __restrict__ Obf, float* __restrict__ Ofp,
    const float* __restrict__ bias, int m0, int n0) {
  __shared__ __align__(16) ush SM[2][16384];
  const int tid = threadIdx.x, lane = tid & 63, wid = tid >> 6;
  const int l16 = lane & 15, lg = lane >> 4;
  const int wr = wid >> 1, wc = wid & 1;

  const f32x4 z4 = {0.f, 0.f, 0.f, 0.f};
  f32x4 acc[4][4];
#pragma unroll
  for (int i = 0; i < 4; i++)
#pragma unroll
    for (int j = 0; j < 4; j++) acc[i][j] = z4;

  stage_tile(A, W, &SM[0][0], m0, n0, 0, wid, lane);
  __syncthreads();
  int cur = 0;
#pragma unroll 1
  for (int t = 0; t < 8; t++) {
    if (t < 7) stage_tile(A, W, &SM[cur ^ 1][0], m0, n0, (t + 1) * 64, wid, lane);
    const ush* At = &SM[cur][0];
    const ush* Bt = &SM[cur][8192];
    s16v8 af[4][2], bf2[4][2];
#pragma unroll
    for (int ms = 0; ms < 4; ms++)
#pragma unroll
      for (int ks = 0; ks < 2; ks++)
        af[ms][ks] = ldsfrag(At, wr * 64 + ms * 16 + l16, ks * 4 + lg);
#pragma unroll
    for (int ns = 0; ns < 4; ns++)
#pragma unroll
      for (int ks = 0; ks < 2; ks++)
        bf2[ns][ks] = ldsfrag(Bt, wc * 64 + ns * 16 + l16, ks * 4 + lg);
#pragma unroll
    for (int ms = 0; ms < 4; ms++)
#pragma unroll
      for (int ns = 0; ns < 4; ns++)
#pragma unroll
        for (int ks = 0; ks < 2; ks++)
          acc[ms][ns] = mfma16(af[ms][ks], bf2[ns][ks], acc[ms][ns]);
    __syncthreads();
    cur ^= 1;
  }

  if (OUTMODE == 0) {
    const int gc0 = n0 + wc * 64;
    const float alpha = (gc0 < 512) ? ALPHA_Q : 1.0f;  // Q carries 1/8*log2e
    ush* cw = &SM[0][0] + wid * 4096;
#pragma unroll
    for (int ms = 0; ms < 4; ms++)
#pragma unroll
      for (int ns = 0; ns < 4; ns++)
#pragma unroll
        for (int r = 0; r < 4; r++) {
          int row = ms * 16 + lg * 4 + r;
          int col = ns * 16 + l16;
          int sw = (((col >> 3) ^ (row & 7)) << 3) + (col & 7);
          cw[row * 64 + sw] = f2bf(acc[ms][ns][r] * alpha);
        }
    __syncthreads();
    const int z = gc0 >> 9, jl = gc0 & 511;
    ush* og = Obf + (size_t)z * 4194304 + (size_t)(m0 + wr * 64) * 512 + jl;
#pragma unroll
    for (int i = 0; i < 8; i++) {
      int row = i * 8 + (lane >> 3), ch = lane & 7;
      s16v8 v = ldsfrag(cw, row, ch);
      *(s16v8*)(og + (size_t)row * 512 + ch * 8) = v;
    }
  } else {
#pragma unroll
    for (int ms = 0; ms < 4; ms++)
#pragma unroll
      for (int ns = 0; ns < 4; ns++) {
        int gcol = n0 + wc * 64 + ns * 16 + l16;
#pragma unroll
        for (int r = 0; r < 4; r++) {
          int grow = m0 + wr * 64 + ms * 16 + lg * 4 + r;
          Ofp[(size_t)grow * 512 + gcol] = acc[ms][ns][r] + bias[gcol];
        }
      }
  }
}

__global__ __launch_bounds__(256) void k_gemm_qkv(
    const ush* __restrict__ Xb, const ush* __restrict__ Wb,
    ush* __restrict__ QKV) {
  gemm2<0>(Xb, Wb, QKV, nullptr, nullptr, blockIdx.x * 128, blockIdx.y * 128);
}

__global__ __launch_bounds__(256) void k_gemm_out(
    const ush* __restrict__ AO, const ush* __restrict__ Wob,
    float* __restrict__ out, const float* __restrict__ bias) {
  gemm2<1>(AO, Wob, nullptr, out, bias, blockIdx.x * 128, blockIdx.y * 128);
}

// ---------------------------------------------------------------------------
// k_kf: pure layout transform Kb -> fragment-linear KF.
// chunk ((tp*8+kcg)*2+ks)*64+lane <- K[(tp*128+kcg*16+l16)*64 + ks*32+lg*8..+7]
// LDS-staged so global read AND write are 16B/lane coalesced.
// grid: 512 = 8 xcd x 4 bh x 16 tp.
// ---------------------------------------------------------------------------
__global__ __launch_bounds__(256) void k_kf(
    const ush* __restrict__ Kb, ush* __restrict__ KF) {
  const int wg = blockIdx.x;
  const int xcd = wg & 7, slot = wg >> 3;
  const int bh = xcd * 4 + (slot >> 4), tp = slot & 15;
  const int b = bh >> 3, h = bh & 7;
  const size_t base = (size_t)b * BATCH_STRIDE + h * HEAD_STRIDE;
  const ush* Kg = Kb + base + tp * 8192;   // 128 k-rows x 64
  ush* kfh = KF + base + tp * 8192;

  __shared__ __align__(16) ush Lp[128 * 80];   // 80-padded rows (16B aligned)
  const int tid = threadIdx.x;

#pragma unroll
  for (int i = 0; i < 4; i++) {
    int cid = i * 256 + tid;
    int row = cid >> 3, ch = cid & 7;
    *(uint4*)(Lp + row * 80 + ch * 8) =
        *(const uint4*)(Kg + (size_t)row * 64 + ch * 8);
  }
  __syncthreads();
#pragma unroll
  for (int i = 0; i < 4; i++) {
    int c = i * 256 + tid;
    int kcg = c >> 7, ks = (c >> 6) & 1, lt = c & 63;
    int row = kcg * 16 + (lt & 15), col = ks * 32 + (lt >> 4) * 8;
    *(uint4*)(kfh + (size_t)c * 8) = *(const uint4*)(Lp + row * 80 + col);
  }
}

// ---------------------------------------------------------------------------
// k_colv (round-9 exact): per (tp: 128 k-rows, bh): Z[k] = sum_q 2^(s'[q,k])
// via swapped-QK (K frags in regs, Q direct), then Vn = V/Z emitted in
// fragment-linear layout VF.  grid: 512 = 8 xcd x 4 bh x 16 tp.
// ---------------------------------------------------------------------------
__global__ __launch_bounds__(256) void k_colv(
    const ush* __restrict__ Qb, const ush* __restrict__ Kb,
    const ush* __restrict__ Vb, ush* __restrict__ VF) {
  const int wg = blockIdx.x;
  const int xcd = wg & 7, slot = wg >> 3;
  const int bh = xcd * 4 + (slot >> 4), tp = slot & 15;
  const int b = bh >> 3, h = bh & 7;
  const size_t base = (size_t)b * BATCH_STRIDE + h * HEAD_STRIDE;
  const ush* Qg = Qb + base;
  const ush* Kg = Kb + base + tp * 8192;   // 128 k-rows x 64
  const ush* Vg = Vb + base + tp * 8192;
  ush* vfh = VF + base + tp * 8192;        // 1024 chunks x 8 shorts

  __shared__ float Zp[512];
  __shared__ float invZ[128];
  __shared__ __align__(16) ush L[128][72];

  const int tid = threadIdx.x, lane = tid & 63, wid = tid >> 6;
  const int l16 = lane & 15, lg = lane >> 4;

  // V tile (128x64) loaded early; latency hidden under the Z pass
  uint4 vr[4];
#pragma unroll
  for (int i = 0; i < 4; i++) {
    int cid = tid * 4 + i;
    vr[i] = *(const uint4*)(Vg + (size_t)(cid >> 3) * 64 + (cid & 7) * 8);
  }

  // K fragments (A-operand): rows kc*16+l16, hd = ks*32 + lg*8..+7
  s16v8 kf[8][2];
#pragma unroll
  for (int kc = 0; kc < 8; kc++)
#pragma unroll
    for (int ks = 0; ks < 2; ks++)
      kf[kc][ks] = *(const s16v8*)(Kg + (size_t)(kc * 16 + l16) * 64 + ks * 32 + lg * 8);

  const f32x4 z4 = {0.f, 0.f, 0.f, 0.f};
  f32x4 zacc[8];
#pragma unroll
  for (int kc = 0; kc < 8; kc++) zacc[kc] = z4;

#pragma unroll 1
  for (int t = 0; t < 8; t++) {
    size_t q0 = (size_t)(t * 4 + wid) * 64;
#pragma unroll
    for (int ms = 0; ms < 4; ms++) {
      const ush* qrow = Qg + (q0 + ms * 16 + l16) * 64;
      s16v8 qf0 = *(const s16v8*)(qrow + lg * 8);
      s16v8 qf1 = *(const s16v8*)(qrow + 32 + lg * 8);
      __builtin_amdgcn_s_setprio(1);
#pragma unroll
      for (int kc = 0; kc < 8; kc++) {
        f32x4 s = mfma16(kf[kc][0], qf0, z4);
        s = mfma16(kf[kc][1], qf1, s);
#pragma unroll
        for (int r = 0; r < 4; r++) zacc[kc][r] += fexp2(s[r]);
      }
      __builtin_amdgcn_s_setprio(0);
    }
  }

  // V tile into LDS [k][d] (padded rows) while reducing Z
#pragma unroll
  for (int i = 0; i < 4; i++) {
    int cid = tid * 4 + i;
    *(uint4*)(&L[cid >> 3][(cid & 7) * 8]) = vr[i];
  }

  // per-wave partial: sum over the wave's 512 q (l16 groups)
#pragma unroll
  for (int kc = 0; kc < 8; kc++)
#pragma unroll
    for (int r = 0; r < 4; r++) {
      float v = zacc[kc][r];
      v += __shfl_xor(v, 1); v += __shfl_xor(v, 2);
      v += __shfl_xor(v, 4); v += __shfl_xor(v, 8);
      if (l16 == 0) Zp[wid * 128 + kc * 16 + lg * 4 + r] = v;
    }
  __syncthreads();
  if (tid < 128)
    invZ[tid] = 1.0f / (Zp[tid] + Zp[128 + tid] + Zp[256 + tid] + Zp[384 + tid]);
  __syncthreads();

  // emit fragment-linear VF: chunk c -> (dt, wid_t, lane_t)
#pragma unroll
  for (int i = 0; i < 4; i++) {
    int c = tid * 4 + i;
    int dt = c >> 8, wid_t = (c >> 6) & 3, lane_t = c & 63;
    int d = dt * 16 + (lane_t & 15);
    int kA = wid_t * 16 + ((lane_t >> 4) << 2);
    ush tmp[8];
#pragma unroll
    for (int j = 0; j < 4; j++)
      tmp[j] = f2bf(bf2f(L[kA + j][d]) * invZ[kA + j]);
#pragma unroll
    for (int j = 0; j < 4; j++)
      tmp[4 + j] = f2bf(bf2f(L[kA + 64 + j][d]) * invZ[kA + 64 + j]);
    *(uint4*)(vfh + c * 8) = *(const uint4*)tmp;
  }
}

// ---------------------------------------------------------------------------
// k_attn: out[q,d] = sum_k 2^(s'[q,k]) * Vn[k,d]
// Block: 64 q rows; 4 waves each own a 16-k slice of each 64-k tile; two
// tiles paired per iter (128 k). Swapped QK (A=K) => P in exact A-frag layout.
// K via KF, Vn via VF — all loads coalesced dwordx4; NO LDS/barriers in loop.
// Explicit 1-ahead K prefetch (named dbuf kc/kn, fully unrolled).
// ---------------------------------------------------------------------------
__global__ __launch_bounds__(256) void k_attn(
    const ush* __restrict__ Qb, const ush* __restrict__ KF,
    const ush* __restrict__ VF, ush* __restrict__ AO) {
  const int wg = blockIdx.x;
  const int xcd = wg & 7, slot = wg >> 3;
  const int bh = xcd * 4 + (slot >> 5), qb = slot & 31;
  const int b = bh >> 3, h = bh & 7;
  const size_t base = (size_t)b * BATCH_STRIDE + h * HEAD_STRIDE;
  const ush* Qg = Qb + base + qb * 4096;   // 64 q rows x 64 dims
  const ush* kfh = KF + base;              // fragment-linear K
  const ush* vfh = VF + base;              // fragment-linear Vn
  ush* aog = AO + base + qb * 4096;

  __shared__ __align__(16) char smraw[32768];  // epilogue only: 2 x 16KB

  const int tid = threadIdx.x, lane = tid & 63, wid = tid >> 6;
  const int l16 = lane & 15, lg = lane >> 4;

  // Q fragments direct from global (held whole kernel)
  s16v8 qa[4][2];
#pragma unroll
  for (int ms = 0; ms < 4; ms++)
#pragma unroll
    for (int ks = 0; ks < 2; ks++)
      qa[ms][ks] = *(const s16v8*)(Qg + (size_t)(ms * 16 + l16) * 64 + ks * 32 + lg * 8);

  const f32x4 z4 = {0.f, 0.f, 0.f, 0.f};
  f32x4 oacc[4][4];
#pragma unroll
  for (int i = 0; i < 4; i++)
#pragma unroll
    for (int j = 0; j < 4; j++) oacc[i][j] = z4;

  const ush* krow = kfh + (size_t)wid * 1024 + (size_t)lane * 8;
  const ush* vrow = vfh + (size_t)(wid * 64 + lane) * 8;

  s16v8 kc0[2], kc1[2], kn0[2], kn1[2];
  {
    const ush* kr = krow;
    kc0[0] = *(const s16v8*)(kr);
    kc0[1] = *(const s16v8*)(kr + 512);
    kc1[0] = *(const s16v8*)(kr + 4096);
    kc1[1] = *(const s16v8*)(kr + 4096 + 512);
  }

#define ATTN_BODY(T, K0, K1)                                                 \
  {                                                                          \
    uint4 vbu[4];                                                            \
    _Pragma("unroll")                                                        \
    for (int dt = 0; dt < 4; dt++)                                           \
      vbu[dt] = *(const uint4*)(vrow + (size_t)((T) * 16 + dt * 4) * 512);   \
    __builtin_amdgcn_s_setprio(1);                                           \
    _Pragma("unroll")                                                        \
    for (int ms = 0; ms < 4; ms++) {                                         \
      f32x4 sA = mfma16(K0[0], qa[ms][0], z4);                               \
      sA = mfma16(K0[1], qa[ms][1], sA);                                     \
      f32x4 sB = mfma16(K1[0], qa[ms][0], z4);                               \
      sB = mfma16(K1[1], qa[ms][1], sB);                                     \
      uint4 pu;                                                              \
      pu.x = bfpack(fexp2(sA[0]), fexp2(sA[1]));                             \
      pu.y = bfpack(fexp2(sA[2]), fexp2(sA[3]));                             \
      pu.z = bfpack(fexp2(sB[0]), fexp2(sB[1]));                             \
      pu.w = bfpack(fexp2(sB[2]), fexp2(sB[3]));                             \
      s16v8 pa = __builtin_bit_cast(s16v8, pu);                              \
      _Pragma("unroll")                                                      \
      for (int dt = 0; dt < 4; dt++)                                         \
        oacc[ms][dt] =                                                       \
            mfma16(pa, __builtin_bit_cast(s16v8, vbu[dt]), oacc[ms][dt]);    \
    }                                                                        \
    __builtin_amdgcn_s_setprio(0);                                           \
  }

#pragma unroll
  for (int tph = 0; tph < 8; tph++) {
    const int t0 = tph * 2, t1 = t0 + 1;
    {
      const ush* kr = krow + (size_t)t1 * 8192;
      kn0[0] = *(const s16v8*)(kr);
      kn0[1] = *(const s16v8*)(kr + 512);
      kn1[0] = *(const s16v8*)(kr + 4096);
      kn1[1] = *(const s16v8*)(kr + 4096 + 512);
    }
    ATTN_BODY(t0, kc0, kc1);
    if (tph < 7) {
      const ush* kr = krow + (size_t)(t0 + 2) * 8192;
      kc0[0] = *(const s16v8*)(kr);
      kc0[1] = *(const s16v8*)(kr + 512);
      kc1[0] = *(const s16v8*)(kr + 4096);
      kc1[1] = *(const s16v8*)(kr + 4096 + 512);
    }
    ATTN_BODY(t1, kn0, kn1);
  }
#undef ATTN_BODY

  // ---- cross-wave k-slice reduction: slot-major, conflict-free ----
  float* red = (float*)smraw;
  if (wid >= 2) {
    float* rg = red + (wid - 2) * 4096;
#pragma unroll
    for (int ms = 0; ms < 4; ms++)
#pragma unroll
      for (int dt = 0; dt < 4; dt++)
        *(f32x4*)(rg + (ms * 4 + dt) * 256 + lane * 4) = oacc[ms][dt];
  }
  __syncthreads();
  if (wid < 2) {
    float* rg = red + wid * 4096;
#pragma unroll
    for (int ms = 0; ms < 4; ms++)
#pragma unroll
      for (int dt = 0; dt < 4; dt++)
        oacc[ms][dt] += *(const f32x4*)(rg + (ms * 4 + dt) * 256 + lane * 4);
  }
  __syncthreads();
  if (wid == 1) {
#pragma unroll
    for (int ms = 0; ms < 4; ms++)
#pragma unroll
      for (int dt = 0; dt < 4; dt++)
        *(f32x4*)(red + (ms * 4 + dt) * 256 + lane * 4) = oacc[ms][dt];
  }
  __syncthreads();
  if (wid == 0) {
#pragma unroll
    for (int ms = 0; ms < 4; ms++)
#pragma unroll
      for (int dt = 0; dt < 4; dt++)
        oacc[ms][dt] += *(const f32x4*)(red + (ms * 4 + dt) * 256 + lane * 4);
  }
  __syncthreads();   // all reads done before out-tile overwrites region 0
  ush* ot = (ush*)smraw;   // 64x64 bf16 out tile
  if (wid == 0) {
#pragma unroll
    for (int ms = 0; ms < 4; ms++)
#pragma unroll
      for (int dt = 0; dt < 4; dt++)
#pragma unroll
        for (int r = 0; r < 4; r++)
          ot[(ms * 16 + lg * 4 + r) * 64 + dt * 16 + l16] = f2bf(oacc[ms][dt][r]);
  }
  __syncthreads();
#pragma unroll
  for (int rd = 0; rd < 2; rd++) {
    int id = rd * 256 + tid;
    *(s16v8*)(aog + id * 8) = *(const s16v8*)(ot + id * 8);
  }
}

// ---------------------------------------------------------------------------
extern "C" void kernel_launch(void* const* d_in, const int* in_sizes, int n_in,
                              void* d_out, int out_size, void* d_ws, size_t ws_size,
                              hipStream_t stream) {
  const float* X  = (const float*)d_in[0];
  const float* Wq = (const float*)d_in[1];
  const float* Wk = (const float*)d_in[2];
  const float* Wv = (const float*)d_in[3];
  const float* Wo = (const float*)d_in[4];
  const float* bo = (const float*)d_in[5];

  ush* Qb  = (ush*)d_ws;          // QKV contiguous: 3 x 4M bf16
  ush* Kb  = Qb + 4194304;
  ush* Vb  = Kb + 4194304;
  ush* VF  = Vb + 4194304;        // fragment-linear Vn per head
  ush* AO  = VF + 4194304;
  ush* Xb  = AO + 4194304;        // X bf16; KF aliases it (dead after qkv GEMM)
  ush* Wb  = Xb + 4194304;        // 4 x 262144 (Wq,Wk,Wv,Wo)
  ush* KF  = Xb;                  // fragment-linear K per head

  k_convert<<<5120, 256, 0, stream>>>(X, Wq, Wk, Wv, Wo, Xb, Wb);
  k_gemm_qkv<<<dim3(64, 12), 256, 0, stream>>>(Xb, Wb, Qb);
  k_kf<<<512, 256, 0, stream>>>(Kb, KF);
  k_colv<<<512, 256, 0, stream>>>(Qb, Kb, Vb, VF);
  k_attn<<<1024, 256, 0, stream>>>(Qb, KF, VF, AO);
  k_gemm_out<<<dim3(64, 4), 256, 0, stream>>>(AO, Wb + 3 * 262144, (float*)d_out, bo);
}